// Round 7
// baseline (257.393 us; speedup 1.0000x reference)
//
#include <hip/hip_runtime.h>
#include <hip/hip_bf16.h>
#include <math.h>

#define B_  4
#define T_  2048
#define D_  1024
#define H_  16
#define HD_ 64
#define U_  38
#define M_  (B_*T_)   // 8192
#define NCW_ 32       // 64-j chunks per head

typedef __attribute__((ext_vector_type(8))) short bf16x8;
typedef __attribute__((ext_vector_type(4))) float f32x4;

__device__ __forceinline__ short f2b(float f) {
    __hip_bfloat16 b = __float2bfloat16(f);
    return *(short*)&b;
}
__device__ __forceinline__ float b2f(short s) {
    __hip_bfloat16 b = *(__hip_bfloat16*)&s;
    return __bfloat162float(b);
}
__device__ __forceinline__ unsigned pack2(float lo, float hi) {
    unsigned a = (unsigned short)f2b(lo);
    unsigned b = ((unsigned)(unsigned short)f2b(hi)) << 16;
    return a | b;
}

__device__ __forceinline__ void gload16(const void* g, void* l) {
    __builtin_amdgcn_global_load_lds(
        (const __attribute__((address_space(1))) unsigned int*)g,
        (__attribute__((address_space(3))) unsigned int*)l,
        16, 0, 0);
}

// ---------------------------------------------------------------------------
// x [8192][1024] fp32 -> xh, xl bf16 (hi + residual-lo split)
// ---------------------------------------------------------------------------
__global__ __launch_bounds__(256) void convx_kernel(
    const float* __restrict__ x, short* __restrict__ xh, short* __restrict__ xl)
{
    const size_t i = ((size_t)blockIdx.x * 256 + threadIdx.x) * 4;
    float4 v = *(const float4*)(x + i);
    short4 h, l;
    h.x = f2b(v.x); l.x = f2b(v.x - b2f(h.x));
    h.y = f2b(v.y); l.y = f2b(v.y - b2f(h.y));
    h.z = f2b(v.z); l.z = f2b(v.z - b2f(h.z));
    h.w = f2b(v.w); l.w = f2b(v.w - b2f(h.w));
    *(short4*)(xh + i) = h;
    *(short4*)(xl + i) = l;
}

// ---------------------------------------------------------------------------
// Transpose weights to [n][k] bf16.
// z=0: Wq -> wq3 [n][3072] = [wh | wh | wl]  (for the K=3072 q-GEMM)
// z=1: Wk -> wkvt rows 0..1023. z=2: Wv -> wkvt rows 1024..2047.
// ---------------------------------------------------------------------------
__global__ __launch_bounds__(256) void convw_kernel(
    const float* __restrict__ Wq, const float* __restrict__ Wk, const float* __restrict__ Wv,
    short* __restrict__ wq3, short* __restrict__ wkvt)
{
    __shared__ float tile[32][33];
    const int which = blockIdx.z;
    const float* W = which == 0 ? Wq : (which == 1 ? Wk : Wv);
    const int k0 = blockIdx.y * 32, n0 = blockIdx.x * 32;
    const int tx = threadIdx.x & 31, ty = threadIdx.x >> 5;
    #pragma unroll
    for (int r = ty; r < 32; r += 8)
        tile[r][tx] = W[(size_t)(k0 + r) * D_ + n0 + tx];
    __syncthreads();
    #pragma unroll
    for (int r = ty; r < 32; r += 8) {
        float v = tile[tx][r];                 // W[k0+tx][n0+r]
        if (which == 0) {
            short h = f2b(v);
            short l = f2b(v - b2f(h));
            size_t base = (size_t)(n0 + r) * 3072 + k0 + tx;
            wq3[base] = h;
            wq3[base + 1024] = h;
            wq3[base + 2048] = l;
        } else {
            wkvt[(size_t)(which - 1) * D_ * D_ + (size_t)(n0 + r) * D_ + k0 + tx] = f2b(v);
        }
    }
}

// ---------------------------------------------------------------------------
// K/V projection: counted-vmcnt 3-buffer pipeline (T3+T4), chunk-XOR swizzle
// (T2-lite, both-sides), setprio (T5). K -> kb [g][t][d]; V -> vt [g][d][t].
// ---------------------------------------------------------------------------
__global__ __launch_bounds__(256) void kv_gemm(
    const short* __restrict__ xh, const short* __restrict__ wkvt,
    const float* __restrict__ bk, const float* __restrict__ bv,
    short* __restrict__ kb, short* __restrict__ vt)
{
    __shared__ short As[3][128 * 32];
    __shared__ short Bs[3][128 * 32];
    const int tid = threadIdx.x, wid = tid >> 6, lane = tid & 63;
    const int m0 = blockIdx.x * 128;
    const int n0 = blockIdx.y * 128;
    const int wr = (wid >> 1) * 64, wc = (wid & 1) * 64;
    const int l15 = lane & 15, gr = lane >> 4;
    const int swz  = (gr ^ (l15 & 3)) * 8;                    // frag-read chunk swizzle
    const int srow = lane >> 2;
    const int scol = ((lane & 3) ^ (srow & 3)) * 8;           // stage-source chunk swizzle

    f32x4 acc[4][4];
    #pragma unroll
    for (int i = 0; i < 4; ++i)
        #pragma unroll
        for (int j = 0; j < 4; ++j)
            acc[i][j] = (f32x4){0.f, 0.f, 0.f, 0.f};

    auto stage = [&](int buf, int kt) {
        const int k0 = kt * 32;
        #pragma unroll
        for (int cc = 0; cc < 2; ++cc) {
            int c = wid + cc * 4;
            int r = c * 16 + srow;
            gload16(xh   + (size_t)(m0 + r) * D_ + k0 + scol, (char*)&As[buf][0] + c * 1024);
            gload16(wkvt + (size_t)(n0 + r) * D_ + k0 + scol, (char*)&Bs[buf][0] + c * 1024);
        }
    };

    stage(0, 0);
    stage(1, 1);
    for (int t = 0; t < 32; ++t) {
        const int cur = t % 3;
        if (t + 2 < 32) stage((t + 2) % 3, t + 2);
        if (t < 30)       asm volatile("s_waitcnt vmcnt(8)" ::: "memory");
        else if (t == 30) asm volatile("s_waitcnt vmcnt(4)" ::: "memory");
        else              asm volatile("s_waitcnt vmcnt(0)" ::: "memory");
        __builtin_amdgcn_s_barrier();
        __builtin_amdgcn_sched_barrier(0);
        bf16x8 a[4], b[4];
        #pragma unroll
        for (int i = 0; i < 4; ++i)
            a[i] = *(bf16x8*)&As[cur][(wr + i * 16 + l15) * 32 + swz];
        #pragma unroll
        for (int j = 0; j < 4; ++j)
            b[j] = *(bf16x8*)&Bs[cur][(wc + j * 16 + l15) * 32 + swz];
        asm volatile("s_waitcnt lgkmcnt(0)" ::: "memory");
        __builtin_amdgcn_sched_barrier(0);
        __builtin_amdgcn_s_barrier();
        __builtin_amdgcn_s_setprio(1);
        #pragma unroll
        for (int i = 0; i < 4; ++i)
            #pragma unroll
            for (int j = 0; j < 4; ++j)
                acc[i][j] = __builtin_amdgcn_mfma_f32_16x16x32_bf16(a[i], b[j], acc[i][j], 0, 0, 0);
        __builtin_amdgcn_s_setprio(0);
    }

    #pragma unroll
    for (int i = 0; i < 4; ++i)
        #pragma unroll
        for (int j = 0; j < 4; ++j)
            #pragma unroll
            for (int r = 0; r < 4; ++r) {
                int row = m0 + wr + i * 16 + gr * 4 + r;
                int col = n0 + wc + j * 16 + l15;
                int bb = row >> 11, t = row & (T_ - 1);
                float bias = (col < D_) ? bk[col] : bv[col - D_];
                float val = acc[i][j][r] + bias;
                int cc2 = col & (D_ - 1);
                int hh = cc2 >> 6, dd = cc2 & 63;
                if (col < D_)
                    kb[(((size_t)bb * H_ + hh) * T_ + t) * HD_ + dd] = f2b(val);
                else
                    vt[(((size_t)bb * H_ + hh) * HD_ + dd) * T_ + t] = f2b(val);
            }
}

// ---------------------------------------------------------------------------
// Q projection as one K=3072 GEMM: A' = [xh | xl | xh], B' = wq3 = [wh;wh;wl]
// -> q = xh*wh + xl*wh + xh*wl, fp32 acc. Same counted-vmcnt pipeline.
// Epilogue: per-(b,h,t) L1 norm (fp32-accurate, ranking) + q values (bf16).
// ---------------------------------------------------------------------------
__global__ __launch_bounds__(256) void q_gemm(
    const short* __restrict__ xh, const short* __restrict__ xl,
    const short* __restrict__ wq3,
    const float* __restrict__ bq, float* __restrict__ qnorm,
    short* __restrict__ qbuf)
{
    __shared__ short As[3][128 * 32];
    __shared__ short Bs[3][128 * 32];
    const int tid = threadIdx.x, wid = tid >> 6, lane = tid & 63;
    const int m0 = blockIdx.x * 128;
    const int n0 = blockIdx.y * 128;
    const int wr = (wid >> 1) * 64, wc = (wid & 1) * 64;
    const int l15 = lane & 15, gr = lane >> 4;
    const int swz  = (gr ^ (l15 & 3)) * 8;
    const int srow = lane >> 2;
    const int scol = ((lane & 3) ^ (srow & 3)) * 8;

    f32x4 acc[4][4];
    #pragma unroll
    for (int i = 0; i < 4; ++i)
        #pragma unroll
        for (int j = 0; j < 4; ++j)
            acc[i][j] = (f32x4){0.f, 0.f, 0.f, 0.f};

    auto stage = [&](int buf, int kt) {
        const short* srcA = (kt >= 32 && kt < 64) ? xl : xh;
        const int ka = (kt * 32) & 1023;
        const int kb2 = kt * 32;
        #pragma unroll
        for (int cc = 0; cc < 2; ++cc) {
            int c = wid + cc * 4;
            int r = c * 16 + srow;
            gload16(srcA + (size_t)(m0 + r) * D_ + ka + scol, (char*)&As[buf][0] + c * 1024);
            gload16(wq3  + (size_t)(n0 + r) * 3072 + kb2 + scol, (char*)&Bs[buf][0] + c * 1024);
        }
    };

    stage(0, 0);
    stage(1, 1);
    for (int t = 0; t < 96; ++t) {
        const int cur = t % 3;
        if (t + 2 < 96) stage((t + 2) % 3, t + 2);
        if (t < 94)       asm volatile("s_waitcnt vmcnt(8)" ::: "memory");
        else if (t == 94) asm volatile("s_waitcnt vmcnt(4)" ::: "memory");
        else              asm volatile("s_waitcnt vmcnt(0)" ::: "memory");
        __builtin_amdgcn_s_barrier();
        __builtin_amdgcn_sched_barrier(0);
        bf16x8 a[4], b[4];
        #pragma unroll
        for (int i = 0; i < 4; ++i)
            a[i] = *(bf16x8*)&As[cur][(wr + i * 16 + l15) * 32 + swz];
        #pragma unroll
        for (int j = 0; j < 4; ++j)
            b[j] = *(bf16x8*)&Bs[cur][(wc + j * 16 + l15) * 32 + swz];
        asm volatile("s_waitcnt lgkmcnt(0)" ::: "memory");
        __builtin_amdgcn_sched_barrier(0);
        __builtin_amdgcn_s_barrier();
        __builtin_amdgcn_s_setprio(1);
        #pragma unroll
        for (int i = 0; i < 4; ++i)
            #pragma unroll
            for (int j = 0; j < 4; ++j)
                acc[i][j] = __builtin_amdgcn_mfma_f32_16x16x32_bf16(a[i], b[j], acc[i][j], 0, 0, 0);
        __builtin_amdgcn_s_setprio(0);
    }

    const int h = (n0 + wc) >> 6;
    #pragma unroll
    for (int i = 0; i < 4; ++i)
        #pragma unroll
        for (int r = 0; r < 4; ++r) {
            int row = m0 + wr + i * 16 + gr * 4 + r;
            float s = 0.f;
            #pragma unroll
            for (int j = 0; j < 4; ++j) {
                int col = n0 + wc + j * 16 + l15;
                float val = acc[i][j][r] + bq[col];
                qbuf[(size_t)row * D_ + col] = f2b(val);
                s += fabsf(val);
            }
            s += __shfl_xor(s, 1);
            s += __shfl_xor(s, 2);
            s += __shfl_xor(s, 4);
            s += __shfl_xor(s, 8);
            if (l15 == 0) {
                int b = row >> 11, t = row & (T_ - 1);
                qnorm[((size_t)b * H_ + h) * T_ + t] = s;
            }
        }
}

// ---------------------------------------------------------------------------
// Top-38 per (b,h): single wave, register-resident, iterative argmax with
// lower-index tie-break.
// ---------------------------------------------------------------------------
__global__ __launch_bounds__(64) void topk_kernel(
    const float* __restrict__ qnorm, int* __restrict__ idxout)
{
    const int g = blockIdx.x;
    const int lane = threadIdx.x;
    float v[32];
    const float* src = qnorm + (size_t)g * T_ + lane * 32;
    #pragma unroll
    for (int i = 0; i < 32; i += 4) {
        float4 t = *(const float4*)(src + i);
        v[i] = t.x; v[i + 1] = t.y; v[i + 2] = t.z; v[i + 3] = t.w;
    }
    unsigned removed = 0;
    float lm; int li;
    #pragma unroll
    for (int it = 0; it < U_ + 1; ++it) {
        lm = -3e38f; li = 0;
        #pragma unroll
        for (int i = 0; i < 32; ++i) {
            bool ok = !((removed >> i) & 1u) && v[i] > lm;
            lm = ok ? v[i] : lm;
            li = ok ? i : li;
        }
        if (it == U_) break;
        float bm = lm; int bi = lane * 32 + li;
        #pragma unroll
        for (int off = 32; off; off >>= 1) {
            float om = __shfl_xor(bm, off);
            int   oi = __shfl_xor(bi, off);
            if (om > bm || (om == bm && oi < bi)) { bm = om; bi = oi; }
        }
        if (lane == 0) idxout[g * U_ + it] = bi;
        if ((bi >> 5) == lane) removed |= 1u << (bi & 31);
    }
}

// ---------------------------------------------------------------------------
// MFMA attention partials (unchanged from round 5).
// ---------------------------------------------------------------------------
__global__ __launch_bounds__(256) void attn_part(
    const short* __restrict__ qbuf, const short* __restrict__ kb,
    const short* __restrict__ vt, const int* __restrict__ idxb,
    float* __restrict__ pm, float* __restrict__ pl, float* __restrict__ po)
{
    __shared__ short qs[48 * 72];          // [u][d] stride 72
    __shared__ short pls[4][48 * 72];      // per-wave P [u][j] stride 72
    __shared__ int   sidx[48];
    const int bid = blockIdx.x;
    const int g = bid & 63;
    const int c = bid >> 6;
    const int b = g >> 4, h = g & 15;
    const int tid = threadIdx.x, wid = tid >> 6, lane = tid & 63;
    const int l15 = lane & 15, gr = lane >> 4;
    const int cw = c * 4 + wid;
    const int j0w = cw * 64;

    if (tid < 48) sidx[tid] = (tid < U_) ? idxb[g * U_ + tid] : 0;
    __syncthreads();
    for (int e = tid; e < 48 * 16; e += 256) {
        int u = e >> 4, d4 = e & 15;
        short4 v = make_short4(0, 0, 0, 0);
        if (u < U_)
            v = *(const short4*)(qbuf + ((size_t)b * T_ + sidx[u]) * D_ + h * HD_ + d4 * 4);
        *(short4*)&qs[u * 72 + d4 * 4] = v;
    }
    __syncthreads();

    int su[3];
    #pragma unroll
    for (int uf = 0; uf < 3; ++uf) su[uf] = sidx[uf * 16 + l15];

    // ---- S^T = K @ q^T ----
    f32x4 accs[3][4];
    #pragma unroll
    for (int uf = 0; uf < 3; ++uf)
        #pragma unroll
        for (int jf = 0; jf < 4; ++jf)
            accs[uf][jf] = (f32x4){0.f, 0.f, 0.f, 0.f};

    bf16x8 ka[4][2], qb[3][2];
    #pragma unroll
    for (int jf = 0; jf < 4; ++jf)
        #pragma unroll
        for (int ks = 0; ks < 2; ++ks)
            ka[jf][ks] = *(const bf16x8*)(kb + ((size_t)g * T_ + j0w + jf * 16 + l15) * HD_ + ks * 32 + gr * 8);
    #pragma unroll
    for (int uf = 0; uf < 3; ++uf)
        #pragma unroll
        for (int ks = 0; ks < 2; ++ks)
            qb[uf][ks] = *(bf16x8*)&qs[(uf * 16 + l15) * 72 + ks * 32 + gr * 8];

    #pragma unroll
    for (int uf = 0; uf < 3; ++uf)
        #pragma unroll
        for (int jf = 0; jf < 4; ++jf) {
            accs[uf][jf] = __builtin_amdgcn_mfma_f32_16x16x32_bf16(ka[jf][0], qb[uf][0], accs[uf][jf], 0, 0, 0);
            accs[uf][jf] = __builtin_amdgcn_mfma_f32_16x16x32_bf16(ka[jf][1], qb[uf][1], accs[uf][jf], 0, 0, 0);
        }

    // ---- mask + per-u softmax partial (over this wave's 64 j) ----
    #pragma unroll
    for (int uf = 0; uf < 3; ++uf) {
        float mm = -3e38f;
        #pragma unroll
        for (int jf = 0; jf < 4; ++jf)
            #pragma unroll
            for (int r = 0; r < 4; ++r) {
                int j = j0w + jf * 16 + gr * 4 + r;
                float s = accs[uf][jf][r] * 0.125f;
                s = (j <= su[uf]) ? s : -1e30f;
                accs[uf][jf][r] = s;
                mm = fmaxf(mm, s);
            }
        mm = fmaxf(mm, __shfl_xor(mm, 16));
        mm = fmaxf(mm, __shfl_xor(mm, 32));
        float ll = 0.f;
        #pragma unroll
        for (int jf = 0; jf < 4; ++jf)
            #pragma unroll
            for (int r = 0; r < 4; ++r) {
                float e = __expf(accs[uf][jf][r] - mm);
                accs[uf][jf][r] = e;
                ll += e;
            }
        ll += __shfl_xor(ll, 16);
        ll += __shfl_xor(ll, 32);
        if (gr == 0) {
            int u = uf * 16 + l15;
            if (u < U_) {
                pm[((size_t)g * NCW_ + cw) * U_ + u] = mm;
                pl[((size_t)g * NCW_ + cw) * U_ + u] = ll;
            }
        }
    }

    // ---- pack P to bf16, per-wave LDS [u][j] ----
    short* pw = &pls[wid][0];
    #pragma unroll
    for (int uf = 0; uf < 3; ++uf)
        #pragma unroll
        for (int jf = 0; jf < 4; ++jf) {
            uint2 wv;
            wv.x = pack2(accs[uf][jf][0], accs[uf][jf][1]);
            wv.y = pack2(accs[uf][jf][2], accs[uf][jf][3]);
            *(uint2*)&pw[(uf * 16 + l15) * 72 + jf * 16 + gr * 4] = wv;
        }

    // ---- PV: O^T[d][u] = V^T @ P^T ----
    bf16x8 va[4][2], pb[3][2];
    #pragma unroll
    for (int df = 0; df < 4; ++df)
        #pragma unroll
        for (int ks = 0; ks < 2; ++ks)
            va[df][ks] = *(const bf16x8*)(vt + ((size_t)g * HD_ + df * 16 + l15) * T_ + j0w + ks * 32 + gr * 8);
    #pragma unroll
    for (int uf = 0; uf < 3; ++uf)
        #pragma unroll
        for (int ks = 0; ks < 2; ++ks)
            pb[uf][ks] = *(bf16x8*)&pw[(uf * 16 + l15) * 72 + ks * 32 + gr * 8];

    f32x4 acco[4][3];
    #pragma unroll
    for (int df = 0; df < 4; ++df)
        #pragma unroll
        for (int uf = 0; uf < 3; ++uf)
            acco[df][uf] = (f32x4){0.f, 0.f, 0.f, 0.f};
    #pragma unroll
    for (int df = 0; df < 4; ++df)
        #pragma unroll
        for (int uf = 0; uf < 3; ++uf) {
            acco[df][uf] = __builtin_amdgcn_mfma_f32_16x16x32_bf16(va[df][0], pb[uf][0], acco[df][uf], 0, 0, 0);
            acco[df][uf] = __builtin_amdgcn_mfma_f32_16x16x32_bf16(va[df][1], pb[uf][1], acco[df][uf], 0, 0, 0);
        }

    #pragma unroll
    for (int df = 0; df < 4; ++df)
        #pragma unroll
        for (int uf = 0; uf < 3; ++uf) {
            int u = uf * 16 + l15;
            if (u < U_) {
                float4 o;
                o.x = acco[df][uf][0]; o.y = acco[df][uf][1];
                o.z = acco[df][uf][2]; o.w = acco[df][uf][3];
                *(float4*)(po + (((size_t)g * NCW_ + cw) * U_ + u) * HD_ + df * 16 + gr * 4) = o;
            }
        }
}

// ---------------------------------------------------------------------------
// Combine: grid (g, u-quad). Dependency-free two-pass merge.
// ---------------------------------------------------------------------------
__global__ __launch_bounds__(256) void attn_combine(
    const float* __restrict__ pm, const float* __restrict__ pl,
    const float* __restrict__ po, float* __restrict__ selo)
{
    const int g = blockIdx.x;
    const int u = blockIdx.y * 4 + (threadIdx.x >> 6);
    const int d = threadIdx.x & 63;
    if (u >= U_) return;

    const float* pmg = pm + (size_t)g * NCW_ * U_ + u;
    const float* plg = pl + (size_t)g * NCW_ * U_ + u;

    float mc[NCW_];
    #pragma unroll
    for (int c = 0; c < NCW_; ++c) mc[c] = pmg[(size_t)c * U_];
    float m = -3e38f;
    #pragma unroll
    for (int c = 0; c < NCW_; ++c) m = fmaxf(m, mc[c]);

    float w[NCW_];
    #pragma unroll
    for (int c = 0; c < NCW_; ++c) w[c] = __expf(mc[c] - m);

    float l = 0.f;
    #pragma unroll
    for (int c = 0; c < NCW_; ++c) l += plg[(size_t)c * U_] * w[c];

    float o = 0.f;
    #pragma unroll
    for (int c = 0; c < NCW_; ++c)
        o += po[(((size_t)g * NCW_ + c) * U_ + u) * HD_ + d] * w[c];

    selo[((size_t)g * U_ + u) * HD_ + d] = o / l;
}

// ---------------------------------------------------------------------------
__global__ __launch_bounds__(256) void fill_kernel(
    const float* __restrict__ bo, float* __restrict__ out)
{
    const size_t i = (size_t)blockIdx.x * 256 + threadIdx.x;   // float4 index
    float4 bv = *(const float4*)(bo + ((i & 255) << 2));
    *(float4*)(out + i * 4) = bv;
}

__global__ __launch_bounds__(256) void oproj_kernel(
    const float* __restrict__ selo, const int* __restrict__ idxb,
    const float* __restrict__ Wo, float* __restrict__ out)
{
    __shared__ float sel[64];
    const int blk = blockIdx.x;
    const int h = (blk / U_) % H_;
    const int b = blk / (U_ * H_);
    const int t = idxb[blk];
    const int tid = threadIdx.x;
    if (tid < 64) sel[tid] = selo[(size_t)blk * HD_ + tid];
    __syncthreads();
    float* orow = out + ((size_t)b * T_ + t) * D_;
    #pragma unroll
    for (int rep = 0; rep < 4; ++rep) {
        int n = tid + rep * 256;
        float c = 0.f;
        #pragma unroll 8
        for (int dd = 0; dd < 64; ++dd)
            c += sel[dd] * Wo[(size_t)(h * HD_ + dd) * D_ + n];
        atomicAdd(orow + n, c);
    }
}

// ---------------------------------------------------------------------------
extern "C" void kernel_launch(void* const* d_in, const int* in_sizes, int n_in,
                              void* d_out, int out_size, void* d_ws, size_t ws_size,
                              hipStream_t stream)
{
    const float* x  = (const float*)d_in[0];
    const float* Wq = (const float*)d_in[1];
    const float* bq = (const float*)d_in[2];
    const float* Wk = (const float*)d_in[3];
    const float* bk = (const float*)d_in[4];
    const float* Wv = (const float*)d_in[5];
    const float* bv = (const float*)d_in[6];
    const float* Wo = (const float*)d_in[7];
    const float* bo = (const float*)d_in[8];
    float* out = (float*)d_out;

    char* ws = (char*)d_ws;
    short* xh    = (short*)(ws);                        // 16,777,216
    short* xl    = (short*)(ws + 16777216);             // 16,777,216  end 33,554,432
    short* wq3   = (short*)(ws + 33554432);             //  6,291,456  end 39,845,888
    short* kb    = (short*)(ws + 39845888);             // 16,777,216  end 56,623,104
    short* vt    = (short*)(ws + 56623104);             // 16,777,216  end 73,400,320
    float* qnorm = (float*)(ws + 73400320);             //    524,288  end 73,924,608
    int*   idxb  = (int*)  (ws + 73924608);             //     16,384  end 73,940,992
    float* selo  = (float*)(ws + 73940992);             //    622,592  end 74,563,584
    short* qbuf  = (short*)(ws + 74563584);             // 16,777,216  end 91,340,800
    short* wkvt  = (short*)(ws + 74563584);             // ALIAS of qbuf: dead before q_gemm writes qbuf
    // partials overlay xh/xl (dead after the GEMMs):
    float* po    = (float*)(ws);                        // 19,922,944
    float* pm    = (float*)(ws + 19922944);             //    311,296
    float* pl    = (float*)(ws + 20234240);             //    311,296

    convx_kernel<<<M_ * D_ / 1024, 256, 0, stream>>>(x, xh, xl);
    convw_kernel<<<dim3(32, 32, 3), 256, 0, stream>>>(Wq, Wk, Wv, wq3, wkvt);
    kv_gemm<<<dim3(M_ / 128, 16), 256, 0, stream>>>(xh, wkvt, bk, bv, kb, vt);
    q_gemm<<<dim3(M_ / 128, 8), 256, 0, stream>>>(xh, xl, wq3, bq, qnorm, qbuf);
    topk_kernel<<<B_ * H_, 64, 0, stream>>>(qnorm, idxb);
    attn_part<<<64 * 8, 256, 0, stream>>>(qbuf, kb, vt, idxb, pm, pl, po);
    attn_combine<<<dim3(B_ * H_, (U_ + 3) / 4), 256, 0, stream>>>(pm, pl, po, selo);
    fill_kernel<<<(M_ * D_ / 4) / 256, 256, 0, stream>>>(bo, out);
    oproj_kernel<<<B_ * H_ * U_, 256, 0, stream>>>(selo, idxb, Wo, out);
}

// Round 8
// 237.342 us; speedup vs baseline: 1.0845x; 1.0845x over previous
//
#include <hip/hip_runtime.h>
#include <hip/hip_bf16.h>
#include <math.h>

#define B_  4
#define T_  2048
#define D_  1024
#define H_  16
#define HD_ 64
#define U_  38
#define M_  (B_*T_)   // 8192
#define NCW_ 32       // 64-j chunks per head

typedef __attribute__((ext_vector_type(8))) short bf16x8;
typedef __attribute__((ext_vector_type(4))) float f32x4;

__device__ __forceinline__ short f2b(float f) {
    __hip_bfloat16 b = __float2bfloat16(f);
    return *(short*)&b;
}
__device__ __forceinline__ float b2f(short s) {
    __hip_bfloat16 b = *(__hip_bfloat16*)&s;
    return __bfloat162float(b);
}
__device__ __forceinline__ unsigned pack2(float lo, float hi) {
    unsigned a = (unsigned short)f2b(lo);
    unsigned b = ((unsigned)(unsigned short)f2b(hi)) << 16;
    return a | b;
}

__device__ __forceinline__ void gload16(const void* g, void* l) {
    __builtin_amdgcn_global_load_lds(
        (const __attribute__((address_space(1))) unsigned int*)g,
        (__attribute__((address_space(3))) unsigned int*)l,
        16, 0, 0);
}

// ---------------------------------------------------------------------------
// x [8192][1024] fp32 -> xh, xl bf16 (hi + residual-lo split)
// ---------------------------------------------------------------------------
__global__ __launch_bounds__(256) void convx_kernel(
    const float* __restrict__ x, short* __restrict__ xh, short* __restrict__ xl)
{
    const size_t i = ((size_t)blockIdx.x * 256 + threadIdx.x) * 4;
    float4 v = *(const float4*)(x + i);
    short4 h, l;
    h.x = f2b(v.x); l.x = f2b(v.x - b2f(h.x));
    h.y = f2b(v.y); l.y = f2b(v.y - b2f(h.y));
    h.z = f2b(v.z); l.z = f2b(v.z - b2f(h.z));
    h.w = f2b(v.w); l.w = f2b(v.w - b2f(h.w));
    *(short4*)(xh + i) = h;
    *(short4*)(xl + i) = l;
}

// ---------------------------------------------------------------------------
// Transpose weights to [n][k] bf16.
// z=0: Wq -> wq2 [2][1024][1024] = [wh ; wl]
// z=1: Wk -> wkvt rows 0..1023. z=2: Wv -> wkvt rows 1024..2047.
// ---------------------------------------------------------------------------
__global__ __launch_bounds__(256) void convw_kernel(
    const float* __restrict__ Wq, const float* __restrict__ Wk, const float* __restrict__ Wv,
    short* __restrict__ wq2, short* __restrict__ wkvt)
{
    __shared__ float tile[32][33];
    const int which = blockIdx.z;
    const float* W = which == 0 ? Wq : (which == 1 ? Wk : Wv);
    const int k0 = blockIdx.y * 32, n0 = blockIdx.x * 32;
    const int tx = threadIdx.x & 31, ty = threadIdx.x >> 5;
    #pragma unroll
    for (int r = ty; r < 32; r += 8)
        tile[r][tx] = W[(size_t)(k0 + r) * D_ + n0 + tx];
    __syncthreads();
    #pragma unroll
    for (int r = ty; r < 32; r += 8) {
        float v = tile[tx][r];                 // W[k0+tx][n0+r]
        size_t o = (size_t)(n0 + r) * D_ + k0 + tx;
        if (which == 0) {
            short h = f2b(v);
            wq2[o] = h;
            wq2[o + 1048576] = f2b(v - b2f(h));
        } else {
            wkvt[(size_t)(which - 1) * D_ * D_ + o] = f2b(v);
        }
    }
}

// ---------------------------------------------------------------------------
// FUSED projection GEMM. Grid 1536 blocks:
//   bid <  512 : Q-path. 128x128 tile over (M=8192, N=1024), K=3072 logical
//                (thirds: xh*wh + xl*wh + xh*wl), fp32 acc. Epilogue: L1
//                norm per (b,h,t) + bf16 q values.
//   bid >= 512 : KV-path. 128x128 tile over (M=8192, N=2048), K=1024.
//                Epilogue: +bias, K -> kb [g][t][d], V -> vt [g][d][t].
// Single-buffer stage->sync->MFMA->sync loop (round-5 best) + 2-way-free
// both-sides chunk swizzle (chunk ^= (row>>1)&3). Q blocks first (LPT).
// ---------------------------------------------------------------------------
__global__ __launch_bounds__(256) void gemm_fused(
    const short* __restrict__ xh, const short* __restrict__ xl,
    const short* __restrict__ wq2, const short* __restrict__ wkvt,
    const float* __restrict__ bq, const float* __restrict__ bk,
    const float* __restrict__ bv,
    float* __restrict__ qnorm, short* __restrict__ qbuf,
    short* __restrict__ kb, short* __restrict__ vt)
{
    __shared__ short As[128 * 32];
    __shared__ short Bs[128 * 32];
    const int bid = blockIdx.x;
    const bool isQ = bid < 512;
    const int tid = threadIdx.x, wid = tid >> 6, lane = tid & 63;
    const int l15 = lane & 15, gr = lane >> 4;
    const int lb = isQ ? bid : bid - 512;
    const int m0 = (lb & 63) * 128;
    const int n0 = (lb >> 6) * 128;
    const int wr = (wid >> 1) * 64, wc = (wid & 1) * 64;
    // stage-side swizzle: thread (srow, sc) loads global chunk sc^((srow>>1)&3)
    const int srow = lane >> 2, sc = lane & 3;
    const int scol = (sc ^ ((srow >> 1) & 3)) * 8;
    // read-side swizzle: LDS chunk gr^((l15>>1)&3) holds global chunk gr
    const int swz = (gr ^ ((l15 >> 1) & 3)) * 8;

    f32x4 acc[4][4];
    #pragma unroll
    for (int i = 0; i < 4; ++i)
        #pragma unroll
        for (int j = 0; j < 4; ++j)
            acc[i][j] = (f32x4){0.f, 0.f, 0.f, 0.f};

    const int KT = isQ ? 96 : 32;
    for (int kt = 0; kt < KT; ++kt) {
        // ---- stage tile kt ----
        const short* Asrc;
        const short* Bsrc;
        int ka, kbcol;
        if (isQ) {
            Asrc = (kt >= 32 && kt < 64) ? xl : xh;
            Bsrc = (kt < 64) ? wq2 : (wq2 + 1048576);
            ka = (kt * 32) & 1023;
            kbcol = ka;
        } else {
            Asrc = xh; Bsrc = wkvt;
            ka = kt * 32; kbcol = ka;
        }
        #pragma unroll
        for (int cc = 0; cc < 2; ++cc) {
            int c = wid + cc * 4;
            int r = c * 16 + srow;
            gload16(Asrc + (size_t)(m0 + r) * D_ + ka + scol,    (char*)As + c * 1024);
            gload16(Bsrc + (size_t)(n0 + r) * D_ + kbcol + scol, (char*)Bs + c * 1024);
        }
        __syncthreads();
        bf16x8 a[4], b[4];
        #pragma unroll
        for (int i = 0; i < 4; ++i)
            a[i] = *(bf16x8*)&As[(wr + i * 16 + l15) * 32 + swz];
        #pragma unroll
        for (int j = 0; j < 4; ++j)
            b[j] = *(bf16x8*)&Bs[(wc + j * 16 + l15) * 32 + swz];
        #pragma unroll
        for (int i = 0; i < 4; ++i)
            #pragma unroll
            for (int j = 0; j < 4; ++j)
                acc[i][j] = __builtin_amdgcn_mfma_f32_16x16x32_bf16(a[i], b[j], acc[i][j], 0, 0, 0);
        __syncthreads();
    }

    if (isQ) {
        const int h = (n0 + wc) >> 6;
        #pragma unroll
        for (int i = 0; i < 4; ++i)
            #pragma unroll
            for (int r = 0; r < 4; ++r) {
                int row = m0 + wr + i * 16 + gr * 4 + r;
                float s = 0.f;
                #pragma unroll
                for (int j = 0; j < 4; ++j) {
                    int col = n0 + wc + j * 16 + l15;
                    float val = acc[i][j][r] + bq[col];
                    qbuf[(size_t)row * D_ + col] = f2b(val);
                    s += fabsf(val);
                }
                s += __shfl_xor(s, 1);
                s += __shfl_xor(s, 2);
                s += __shfl_xor(s, 4);
                s += __shfl_xor(s, 8);
                if (l15 == 0) {
                    int b = row >> 11, t = row & (T_ - 1);
                    qnorm[((size_t)b * H_ + h) * T_ + t] = s;
                }
            }
    } else {
        #pragma unroll
        for (int i = 0; i < 4; ++i)
            #pragma unroll
            for (int j = 0; j < 4; ++j)
                #pragma unroll
                for (int r = 0; r < 4; ++r) {
                    int row = m0 + wr + i * 16 + gr * 4 + r;
                    int col = n0 + wc + j * 16 + l15;
                    int bb = row >> 11, t = row & (T_ - 1);
                    float bias = (col < D_) ? bk[col] : bv[col - D_];
                    float val = acc[i][j][r] + bias;
                    int cc2 = col & (D_ - 1);
                    int hh = cc2 >> 6, dd = cc2 & 63;
                    if (col < D_)
                        kb[(((size_t)bb * H_ + hh) * T_ + t) * HD_ + dd] = f2b(val);
                    else
                        vt[(((size_t)bb * H_ + hh) * HD_ + dd) * T_ + t] = f2b(val);
                }
    }
}

// ---------------------------------------------------------------------------
// Top-38 per (b,h): single wave, register-resident, iterative argmax with
// lower-index tie-break.
// ---------------------------------------------------------------------------
__global__ __launch_bounds__(64) void topk_kernel(
    const float* __restrict__ qnorm, int* __restrict__ idxout)
{
    const int g = blockIdx.x;
    const int lane = threadIdx.x;
    float v[32];
    const float* src = qnorm + (size_t)g * T_ + lane * 32;
    #pragma unroll
    for (int i = 0; i < 32; i += 4) {
        float4 t = *(const float4*)(src + i);
        v[i] = t.x; v[i + 1] = t.y; v[i + 2] = t.z; v[i + 3] = t.w;
    }
    unsigned removed = 0;
    float lm; int li;
    #pragma unroll
    for (int it = 0; it < U_ + 1; ++it) {
        lm = -3e38f; li = 0;
        #pragma unroll
        for (int i = 0; i < 32; ++i) {
            bool ok = !((removed >> i) & 1u) && v[i] > lm;
            lm = ok ? v[i] : lm;
            li = ok ? i : li;
        }
        if (it == U_) break;
        float bm = lm; int bi = lane * 32 + li;
        #pragma unroll
        for (int off = 32; off; off >>= 1) {
            float om = __shfl_xor(bm, off);
            int   oi = __shfl_xor(bi, off);
            if (om > bm || (om == bm && oi < bi)) { bm = om; bi = oi; }
        }
        if (lane == 0) idxout[g * U_ + it] = bi;
        if ((bi >> 5) == lane) removed |= 1u << (bi & 31);
    }
}

// ---------------------------------------------------------------------------
// MFMA attention partials (unchanged).
// ---------------------------------------------------------------------------
__global__ __launch_bounds__(256) void attn_part(
    const short* __restrict__ qbuf, const short* __restrict__ kb,
    const short* __restrict__ vt, const int* __restrict__ idxb,
    float* __restrict__ pm, float* __restrict__ pl, float* __restrict__ po)
{
    __shared__ short qs[48 * 72];          // [u][d] stride 72
    __shared__ short pls[4][48 * 72];      // per-wave P [u][j] stride 72
    __shared__ int   sidx[48];
    const int bid = blockIdx.x;
    const int g = bid & 63;
    const int c = bid >> 6;
    const int b = g >> 4, h = g & 15;
    const int tid = threadIdx.x, wid = tid >> 6, lane = tid & 63;
    const int l15 = lane & 15, gr = lane >> 4;
    const int cw = c * 4 + wid;
    const int j0w = cw * 64;

    if (tid < 48) sidx[tid] = (tid < U_) ? idxb[g * U_ + tid] : 0;
    __syncthreads();
    for (int e = tid; e < 48 * 16; e += 256) {
        int u = e >> 4, d4 = e & 15;
        short4 v = make_short4(0, 0, 0, 0);
        if (u < U_)
            v = *(const short4*)(qbuf + ((size_t)b * T_ + sidx[u]) * D_ + h * HD_ + d4 * 4);
        *(short4*)&qs[u * 72 + d4 * 4] = v;
    }
    __syncthreads();

    int su[3];
    #pragma unroll
    for (int uf = 0; uf < 3; ++uf) su[uf] = sidx[uf * 16 + l15];

    // ---- S^T = K @ q^T ----
    f32x4 accs[3][4];
    #pragma unroll
    for (int uf = 0; uf < 3; ++uf)
        #pragma unroll
        for (int jf = 0; jf < 4; ++jf)
            accs[uf][jf] = (f32x4){0.f, 0.f, 0.f, 0.f};

    bf16x8 ka[4][2], qb[3][2];
    #pragma unroll
    for (int jf = 0; jf < 4; ++jf)
        #pragma unroll
        for (int ks = 0; ks < 2; ++ks)
            ka[jf][ks] = *(const bf16x8*)(kb + ((size_t)g * T_ + j0w + jf * 16 + l15) * HD_ + ks * 32 + gr * 8);
    #pragma unroll
    for (int uf = 0; uf < 3; ++uf)
        #pragma unroll
        for (int ks = 0; ks < 2; ++ks)
            qb[uf][ks] = *(bf16x8*)&qs[(uf * 16 + l15) * 72 + ks * 32 + gr * 8];

    #pragma unroll
    for (int uf = 0; uf < 3; ++uf)
        #pragma unroll
        for (int jf = 0; jf < 4; ++jf) {
            accs[uf][jf] = __builtin_amdgcn_mfma_f32_16x16x32_bf16(ka[jf][0], qb[uf][0], accs[uf][jf], 0, 0, 0);
            accs[uf][jf] = __builtin_amdgcn_mfma_f32_16x16x32_bf16(ka[jf][1], qb[uf][1], accs[uf][jf], 0, 0, 0);
        }

    // ---- mask + per-u softmax partial (over this wave's 64 j) ----
    #pragma unroll
    for (int uf = 0; uf < 3; ++uf) {
        float mm = -3e38f;
        #pragma unroll
        for (int jf = 0; jf < 4; ++jf)
            #pragma unroll
            for (int r = 0; r < 4; ++r) {
                int j = j0w + jf * 16 + gr * 4 + r;
                float s = accs[uf][jf][r] * 0.125f;
                s = (j <= su[uf]) ? s : -1e30f;
                accs[uf][jf][r] = s;
                mm = fmaxf(mm, s);
            }
        mm = fmaxf(mm, __shfl_xor(mm, 16));
        mm = fmaxf(mm, __shfl_xor(mm, 32));
        float ll = 0.f;
        #pragma unroll
        for (int jf = 0; jf < 4; ++jf)
            #pragma unroll
            for (int r = 0; r < 4; ++r) {
                float e = __expf(accs[uf][jf][r] - mm);
                accs[uf][jf][r] = e;
                ll += e;
            }
        ll += __shfl_xor(ll, 16);
        ll += __shfl_xor(ll, 32);
        if (gr == 0) {
            int u = uf * 16 + l15;
            if (u < U_) {
                pm[((size_t)g * NCW_ + cw) * U_ + u] = mm;
                pl[((size_t)g * NCW_ + cw) * U_ + u] = ll;
            }
        }
    }

    // ---- pack P to bf16, per-wave LDS [u][j] ----
    short* pw = &pls[wid][0];
    #pragma unroll
    for (int uf = 0; uf < 3; ++uf)
        #pragma unroll
        for (int jf = 0; jf < 4; ++jf) {
            uint2 wv;
            wv.x = pack2(accs[uf][jf][0], accs[uf][jf][1]);
            wv.y = pack2(accs[uf][jf][2], accs[uf][jf][3]);
            *(uint2*)&pw[(uf * 16 + l15) * 72 + jf * 16 + gr * 4] = wv;
        }

    // ---- PV: O^T[d][u] = V^T @ P^T ----
    bf16x8 va[4][2], pb[3][2];
    #pragma unroll
    for (int df = 0; df < 4; ++df)
        #pragma unroll
        for (int ks = 0; ks < 2; ++ks)
            va[df][ks] = *(const bf16x8*)(vt + ((size_t)g * HD_ + df * 16 + l15) * T_ + j0w + ks * 32 + gr * 8);
    #pragma unroll
    for (int uf = 0; uf < 3; ++uf)
        #pragma unroll
        for (int ks = 0; ks < 2; ++ks)
            pb[uf][ks] = *(bf16x8*)&pw[(uf * 16 + l15) * 72 + ks * 32 + gr * 8];

    f32x4 acco[4][3];
    #pragma unroll
    for (int df = 0; df < 4; ++df)
        #pragma unroll
        for (int uf = 0; uf < 3; ++uf)
            acco[df][uf] = (f32x4){0.f, 0.f, 0.f, 0.f};
    #pragma unroll
    for (int df = 0; df < 4; ++df)
        #pragma unroll
        for (int uf = 0; uf < 3; ++uf) {
            acco[df][uf] = __builtin_amdgcn_mfma_f32_16x16x32_bf16(va[df][0], pb[uf][0], acco[df][uf], 0, 0, 0);
            acco[df][uf] = __builtin_amdgcn_mfma_f32_16x16x32_bf16(va[df][1], pb[uf][1], acco[df][uf], 0, 0, 0);
        }

    #pragma unroll
    for (int df = 0; df < 4; ++df)
        #pragma unroll
        for (int uf = 0; uf < 3; ++uf) {
            int u = uf * 16 + l15;
            if (u < U_) {
                float4 o;
                o.x = acco[df][uf][0]; o.y = acco[df][uf][1];
                o.z = acco[df][uf][2]; o.w = acco[df][uf][3];
                *(float4*)(po + (((size_t)g * NCW_ + cw) * U_ + u) * HD_ + df * 16 + gr * 4) = o;
            }
        }
}

// ---------------------------------------------------------------------------
// Combine: grid (g, u-quad). Dependency-free two-pass merge.
// ---------------------------------------------------------------------------
__global__ __launch_bounds__(256) void attn_combine(
    const float* __restrict__ pm, const float* __restrict__ pl,
    const float* __restrict__ po, float* __restrict__ selo)
{
    const int g = blockIdx.x;
    const int u = blockIdx.y * 4 + (threadIdx.x >> 6);
    const int d = threadIdx.x & 63;
    if (u >= U_) return;

    const float* pmg = pm + (size_t)g * NCW_ * U_ + u;
    const float* plg = pl + (size_t)g * NCW_ * U_ + u;

    float mc[NCW_];
    #pragma unroll
    for (int c = 0; c < NCW_; ++c) mc[c] = pmg[(size_t)c * U_];
    float m = -3e38f;
    #pragma unroll
    for (int c = 0; c < NCW_; ++c) m = fmaxf(m, mc[c]);

    float w[NCW_];
    #pragma unroll
    for (int c = 0; c < NCW_; ++c) w[c] = __expf(mc[c] - m);

    float l = 0.f;
    #pragma unroll
    for (int c = 0; c < NCW_; ++c) l += plg[(size_t)c * U_] * w[c];

    float o = 0.f;
    #pragma unroll
    for (int c = 0; c < NCW_; ++c)
        o += po[(((size_t)g * NCW_ + c) * U_ + u) * HD_ + d] * w[c];

    selo[((size_t)g * U_ + u) * HD_ + d] = o / l;
}

// ---------------------------------------------------------------------------
__global__ __launch_bounds__(256) void fill_kernel(
    const float* __restrict__ bo, float* __restrict__ out)
{
    const size_t i = (size_t)blockIdx.x * 256 + threadIdx.x;   // float4 index
    float4 bv = *(const float4*)(bo + ((i & 255) << 2));
    *(float4*)(out + i * 4) = bv;
}

__global__ __launch_bounds__(256) void oproj_kernel(
    const float* __restrict__ selo, const int* __restrict__ idxb,
    const float* __restrict__ Wo, float* __restrict__ out)
{
    __shared__ float sel[64];
    const int blk = blockIdx.x;
    const int h = (blk / U_) % H_;
    const int b = blk / (U_ * H_);
    const int t = idxb[blk];
    const int tid = threadIdx.x;
    if (tid < 64) sel[tid] = selo[(size_t)blk * HD_ + tid];
    __syncthreads();
    float* orow = out + ((size_t)b * T_ + t) * D_;
    #pragma unroll
    for (int rep = 0; rep < 4; ++rep) {
        int n = tid + rep * 256;
        float c = 0.f;
        #pragma unroll 8
        for (int dd = 0; dd < 64; ++dd)
            c += sel[dd] * Wo[(size_t)(h * HD_ + dd) * D_ + n];
        atomicAdd(orow + n, c);
    }
}

// ---------------------------------------------------------------------------
extern "C" void kernel_launch(void* const* d_in, const int* in_sizes, int n_in,
                              void* d_out, int out_size, void* d_ws, size_t ws_size,
                              hipStream_t stream)
{
    const float* x  = (const float*)d_in[0];
    const float* Wq = (const float*)d_in[1];
    const float* bq = (const float*)d_in[2];
    const float* Wk = (const float*)d_in[3];
    const float* bk = (const float*)d_in[4];
    const float* Wv = (const float*)d_in[5];
    const float* bv = (const float*)d_in[6];
    const float* Wo = (const float*)d_in[7];
    const float* bo = (const float*)d_in[8];
    float* out = (float*)d_out;

    char* ws = (char*)d_ws;
    short* xh    = (short*)(ws);                        // 16,777,216
    short* xl    = (short*)(ws + 16777216);             // 16,777,216  end 33,554,432
    short* wq2   = (short*)(ws + 33554432);             //  4,194,304  end 37,748,736  [wh;wl]
    short* wkvt  = (short*)(ws + 37748736);             //  4,194,304  end 41,943,040
    short* kb    = (short*)(ws + 41943040);             // 16,777,216  end 58,720,256
    short* vt    = (short*)(ws + 58720256);             // 16,777,216  end 75,497,472
    float* qnorm = (float*)(ws + 75497472);             //    524,288  end 76,021,760
    int*   idxb  = (int*)  (ws + 76021760);             //     16,384  end 76,038,144
    float* selo  = (float*)(ws + 76038144);             //    622,592  end 76,660,736
    short* qbuf  = (short*)(ws + 76660736);             // 16,777,216  end 93,437,952
    // partials overlay xh/xl (dead after the GEMMs):
    float* po    = (float*)(ws);                        // 19,922,944
    float* pm    = (float*)(ws + 19922944);             //    311,296
    float* pl    = (float*)(ws + 20234240);             //    311,296

    convx_kernel<<<M_ * D_ / 1024, 256, 0, stream>>>(x, xh, xl);
    convw_kernel<<<dim3(32, 32, 3), 256, 0, stream>>>(Wq, Wk, Wv, wq2, wkvt);
    gemm_fused<<<1536, 256, 0, stream>>>(xh, xl, wq2, wkvt, bq, bk, bv,
                                         qnorm, qbuf, kb, vt);
    topk_kernel<<<B_ * H_, 64, 0, stream>>>(qnorm, idxb);
    attn_part<<<64 * 8, 256, 0, stream>>>(qbuf, kb, vt, idxb, pm, pl, po);
    attn_combine<<<dim3(B_ * H_, (U_ + 3) / 4), 256, 0, stream>>>(pm, pl, po, selo);
    fill_kernel<<<(M_ * D_ / 4) / 256, 256, 0, stream>>>(bo, out);
    oproj_kernel<<<B_ * H_ * U_, 256, 0, stream>>>(selo, idxb, Wo, out);
}

// Round 9
// 208.921 us; speedup vs baseline: 1.2320x; 1.1360x over previous
//
#include <hip/hip_runtime.h>
#include <hip/hip_bf16.h>
#include <math.h>

#define B_  4
#define T_  2048
#define D_  1024
#define H_  16
#define HD_ 64
#define U_  38
#define M_  (B_*T_)   // 8192
#define NCW_ 32       // 64-j chunks per head

typedef __attribute__((ext_vector_type(8))) short bf16x8;
typedef __attribute__((ext_vector_type(4))) float f32x4;

__device__ __forceinline__ short f2b(float f) {
    __hip_bfloat16 b = __float2bfloat16(f);
    return *(short*)&b;
}
__device__ __forceinline__ float b2f(short s) {
    __hip_bfloat16 b = *(__hip_bfloat16*)&s;
    return __bfloat162float(b);
}
__device__ __forceinline__ unsigned pack2(float lo, float hi) {
    unsigned a = (unsigned short)f2b(lo);
    unsigned b = ((unsigned)(unsigned short)f2b(hi)) << 16;
    return a | b;
}

__device__ __forceinline__ void gload16(const void* g, void* l) {
    __builtin_amdgcn_global_load_lds(
        (const __attribute__((address_space(1))) unsigned int*)g,
        (__attribute__((address_space(3))) unsigned int*)l,
        16, 0, 0);
}

// ---------------------------------------------------------------------------
// x [8192][1024] fp32 -> xh, xl bf16 (hi + residual-lo split)
// ---------------------------------------------------------------------------
__global__ __launch_bounds__(256) void convx_kernel(
    const float* __restrict__ x, short* __restrict__ xh, short* __restrict__ xl)
{
    const size_t i = ((size_t)blockIdx.x * 256 + threadIdx.x) * 4;
    float4 v = *(const float4*)(x + i);
    short4 h, l;
    h.x = f2b(v.x); l.x = f2b(v.x - b2f(h.x));
    h.y = f2b(v.y); l.y = f2b(v.y - b2f(h.y));
    h.z = f2b(v.z); l.z = f2b(v.z - b2f(h.z));
    h.w = f2b(v.w); l.w = f2b(v.w - b2f(h.w));
    *(short4*)(xh + i) = h;
    *(short4*)(xl + i) = l;
}

// ---------------------------------------------------------------------------
// Transpose weights to [n][k] bf16.
// z=0: Wq -> wq2 [2][1024][1024] = [wh ; wl]
// z=1: Wk -> wkvt rows 0..1023. z=2: Wv -> wkvt rows 1024..2047.
// ---------------------------------------------------------------------------
__global__ __launch_bounds__(256) void convw_kernel(
    const float* __restrict__ Wq, const float* __restrict__ Wk, const float* __restrict__ Wv,
    short* __restrict__ wq2, short* __restrict__ wkvt)
{
    __shared__ float tile[32][33];
    const int which = blockIdx.z;
    const float* W = which == 0 ? Wq : (which == 1 ? Wk : Wv);
    const int k0 = blockIdx.y * 32, n0 = blockIdx.x * 32;
    const int tx = threadIdx.x & 31, ty = threadIdx.x >> 5;
    #pragma unroll
    for (int r = ty; r < 32; r += 8)
        tile[r][tx] = W[(size_t)(k0 + r) * D_ + n0 + tx];
    __syncthreads();
    #pragma unroll
    for (int r = ty; r < 32; r += 8) {
        float v = tile[tx][r];                 // W[k0+tx][n0+r]
        size_t o = (size_t)(n0 + r) * D_ + k0 + tx;
        if (which == 0) {
            short h = f2b(v);
            wq2[o] = h;
            wq2[o + 1048576] = f2b(v - b2f(h));
        } else {
            wkvt[(size_t)(which - 1) * D_ * D_ + o] = f2b(v);
        }
    }
}

// ---------------------------------------------------------------------------
// FUSED projection GEMM, BK=64. Grid 1536 blocks:
//   bid <  512 : Q-path. 128x128 tile, K=3072 logical (16-step thirds:
//                xh*wh, xl*wh, xh*wl), fp32 acc. Epilogue: L1 norm + bf16 q.
//   bid >= 512 : KV-path. 128x128 tile over (M, N=2048), K=1024 (16 steps).
//                Epilogue: +bias, K -> kb [g][t][d], V -> vt [g][d][t]
//                (vt via packed short4 stores: 4 consecutive t per frag).
// Single-buffer stage->sync->2x(ds_read+16 MFMA)->sync loop. Both-sides
// XOR-8 chunk swizzle: LDS slot c of row r holds global chunk c^(r&7);
// 16-lane frag reads spread over 8 x 16B slots = all 32 banks, 2-way free.
// ---------------------------------------------------------------------------
__global__ __launch_bounds__(256) void gemm_fused(
    const short* __restrict__ xh, const short* __restrict__ xl,
    const short* __restrict__ wq2, const short* __restrict__ wkvt,
    const float* __restrict__ bq, const float* __restrict__ bk,
    const float* __restrict__ bv,
    float* __restrict__ qnorm, short* __restrict__ qbuf,
    short* __restrict__ kb, short* __restrict__ vt)
{
    __shared__ short As[128 * 64];
    __shared__ short Bs[128 * 64];
    const int bid = blockIdx.x;
    const bool isQ = bid < 512;
    const int tid = threadIdx.x, wid = tid >> 6, lane = tid & 63;
    const int l15 = lane & 15, gr = lane >> 4;
    const int lb = isQ ? bid : bid - 512;
    const int m0 = (lb & 63) * 128;
    const int n0 = (lb >> 6) * 128;
    const int wr = (wid >> 1) * 64, wc = (wid & 1) * 64;

    f32x4 acc[4][4];
    #pragma unroll
    for (int i = 0; i < 4; ++i)
        #pragma unroll
        for (int j = 0; j < 4; ++j)
            acc[i][j] = (f32x4){0.f, 0.f, 0.f, 0.f};

    const int KT = isQ ? 48 : 16;
    for (int kt = 0; kt < KT; ++kt) {
        const short* Asrc;
        const short* Bsrc;
        int ka;
        if (isQ) {
            const int sec = kt >> 4;
            Asrc = (sec == 1) ? xl : xh;
            Bsrc = wq2 + (sec == 2 ? 1048576 : 0);
            ka = (kt & 15) * 64;
        } else {
            Asrc = xh; Bsrc = wkvt; ka = kt * 64;
        }
        // ---- stage tile kt (1024 x 16B per array; swizzled source) ----
        #pragma unroll
        for (int i = 0; i < 4; ++i) {
            const int e = tid + i * 256;
            const int row = e >> 3;
            const int soff = ((e & 7) ^ (row & 7)) * 8;
            gload16(Asrc + (size_t)(m0 + row) * D_ + ka + soff,
                    (char*)As + i * 4096 + wid * 1024);
            gload16(Bsrc + (size_t)(n0 + row) * D_ + ka + soff,
                    (char*)Bs + i * 4096 + wid * 1024);
        }
        __syncthreads();
        #pragma unroll
        for (int ks = 0; ks < 2; ++ks) {
            bf16x8 a[4], b[4];
            #pragma unroll
            for (int i = 0; i < 4; ++i)
                a[i] = *(bf16x8*)((char*)As + (wr + i * 16 + l15) * 128
                                   + (((ks << 2) | gr) ^ (l15 & 7)) * 16);
            #pragma unroll
            for (int j = 0; j < 4; ++j)
                b[j] = *(bf16x8*)((char*)Bs + (wc + j * 16 + l15) * 128
                                   + (((ks << 2) | gr) ^ (l15 & 7)) * 16);
            #pragma unroll
            for (int i = 0; i < 4; ++i)
                #pragma unroll
                for (int j = 0; j < 4; ++j)
                    acc[i][j] = __builtin_amdgcn_mfma_f32_16x16x32_bf16(a[i], b[j], acc[i][j], 0, 0, 0);
        }
        __syncthreads();
    }

    if (isQ) {
        const int h = (n0 + wc) >> 6;
        #pragma unroll
        for (int i = 0; i < 4; ++i)
            #pragma unroll
            for (int r = 0; r < 4; ++r) {
                int row = m0 + wr + i * 16 + gr * 4 + r;
                float s = 0.f;
                #pragma unroll
                for (int j = 0; j < 4; ++j) {
                    int col = n0 + wc + j * 16 + l15;
                    float val = acc[i][j][r] + bq[col];
                    qbuf[(size_t)row * D_ + col] = f2b(val);
                    s += fabsf(val);
                }
                s += __shfl_xor(s, 1);
                s += __shfl_xor(s, 2);
                s += __shfl_xor(s, 4);
                s += __shfl_xor(s, 8);
                if (l15 == 0) {
                    int b = row >> 11, t = row & (T_ - 1);
                    qnorm[((size_t)b * H_ + h) * T_ + t] = s;
                }
            }
    } else {
        #pragma unroll
        for (int i = 0; i < 4; ++i)
            #pragma unroll
            for (int j = 0; j < 4; ++j) {
                const int col = n0 + wc + j * 16 + l15;
                const int rowb = m0 + wr + i * 16 + gr * 4;
                const int bb = rowb >> 11, t0 = rowb & (T_ - 1);
                if (col < D_) {
                    const int hh = col >> 6, dd = col & 63;
                    const float bias = bk[col];
                    #pragma unroll
                    for (int r = 0; r < 4; ++r)
                        kb[(((size_t)bb * H_ + hh) * T_ + t0 + r) * HD_ + dd] =
                            f2b(acc[i][j][r] + bias);
                } else {
                    const int cc2 = col - D_;
                    const int hh = cc2 >> 6, dd = cc2 & 63;
                    const float bias = bv[cc2];
                    short4 pk;
                    pk.x = f2b(acc[i][j][0] + bias);
                    pk.y = f2b(acc[i][j][1] + bias);
                    pk.z = f2b(acc[i][j][2] + bias);
                    pk.w = f2b(acc[i][j][3] + bias);
                    *(short4*)(vt + (((size_t)bb * H_ + hh) * HD_ + dd) * T_ + t0) = pk;
                }
            }
    }
}

// ---------------------------------------------------------------------------
// Top-38 per (b,h): single wave, register-resident, iterative argmax with
// lower-index tie-break.
// ---------------------------------------------------------------------------
__global__ __launch_bounds__(64) void topk_kernel(
    const float* __restrict__ qnorm, int* __restrict__ idxout)
{
    const int g = blockIdx.x;
    const int lane = threadIdx.x;
    float v[32];
    const float* src = qnorm + (size_t)g * T_ + lane * 32;
    #pragma unroll
    for (int i = 0; i < 32; i += 4) {
        float4 t = *(const float4*)(src + i);
        v[i] = t.x; v[i + 1] = t.y; v[i + 2] = t.z; v[i + 3] = t.w;
    }
    unsigned removed = 0;
    float lm; int li;
    #pragma unroll
    for (int it = 0; it < U_ + 1; ++it) {
        lm = -3e38f; li = 0;
        #pragma unroll
        for (int i = 0; i < 32; ++i) {
            bool ok = !((removed >> i) & 1u) && v[i] > lm;
            lm = ok ? v[i] : lm;
            li = ok ? i : li;
        }
        if (it == U_) break;
        float bm = lm; int bi = lane * 32 + li;
        #pragma unroll
        for (int off = 32; off; off >>= 1) {
            float om = __shfl_xor(bm, off);
            int   oi = __shfl_xor(bi, off);
            if (om > bm || (om == bm && oi < bi)) { bm = om; bi = oi; }
        }
        if (lane == 0) idxout[g * U_ + it] = bi;
        if ((bi >> 5) == lane) removed |= 1u << (bi & 31);
    }
}

// ---------------------------------------------------------------------------
// MFMA attention partials (unchanged).
// ---------------------------------------------------------------------------
__global__ __launch_bounds__(256) void attn_part(
    const short* __restrict__ qbuf, const short* __restrict__ kb,
    const short* __restrict__ vt, const int* __restrict__ idxb,
    float* __restrict__ pm, float* __restrict__ pl, float* __restrict__ po)
{
    __shared__ short qs[48 * 72];          // [u][d] stride 72
    __shared__ short pls[4][48 * 72];      // per-wave P [u][j] stride 72
    __shared__ int   sidx[48];
    const int bid = blockIdx.x;
    const int g = bid & 63;
    const int c = bid >> 6;
    const int b = g >> 4, h = g & 15;
    const int tid = threadIdx.x, wid = tid >> 6, lane = tid & 63;
    const int l15 = lane & 15, gr = lane >> 4;
    const int cw = c * 4 + wid;
    const int j0w = cw * 64;

    if (tid < 48) sidx[tid] = (tid < U_) ? idxb[g * U_ + tid] : 0;
    __syncthreads();
    for (int e = tid; e < 48 * 16; e += 256) {
        int u = e >> 4, d4 = e & 15;
        short4 v = make_short4(0, 0, 0, 0);
        if (u < U_)
            v = *(const short4*)(qbuf + ((size_t)b * T_ + sidx[u]) * D_ + h * HD_ + d4 * 4);
        *(short4*)&qs[u * 72 + d4 * 4] = v;
    }
    __syncthreads();

    int su[3];
    #pragma unroll
    for (int uf = 0; uf < 3; ++uf) su[uf] = sidx[uf * 16 + l15];

    // ---- S^T = K @ q^T ----
    f32x4 accs[3][4];
    #pragma unroll
    for (int uf = 0; uf < 3; ++uf)
        #pragma unroll
        for (int jf = 0; jf < 4; ++jf)
            accs[uf][jf] = (f32x4){0.f, 0.f, 0.f, 0.f};

    bf16x8 ka[4][2], qb[3][2];
    #pragma unroll
    for (int jf = 0; jf < 4; ++jf)
        #pragma unroll
        for (int ks = 0; ks < 2; ++ks)
            ka[jf][ks] = *(const bf16x8*)(kb + ((size_t)g * T_ + j0w + jf * 16 + l15) * HD_ + ks * 32 + gr * 8);
    #pragma unroll
    for (int uf = 0; uf < 3; ++uf)
        #pragma unroll
        for (int ks = 0; ks < 2; ++ks)
            qb[uf][ks] = *(bf16x8*)&qs[(uf * 16 + l15) * 72 + ks * 32 + gr * 8];

    #pragma unroll
    for (int uf = 0; uf < 3; ++uf)
        #pragma unroll
        for (int jf = 0; jf < 4; ++jf) {
            accs[uf][jf] = __builtin_amdgcn_mfma_f32_16x16x32_bf16(ka[jf][0], qb[uf][0], accs[uf][jf], 0, 0, 0);
            accs[uf][jf] = __builtin_amdgcn_mfma_f32_16x16x32_bf16(ka[jf][1], qb[uf][1], accs[uf][jf], 0, 0, 0);
        }

    // ---- mask + per-u softmax partial (over this wave's 64 j) ----
    #pragma unroll
    for (int uf = 0; uf < 3; ++uf) {
        float mm = -3e38f;
        #pragma unroll
        for (int jf = 0; jf < 4; ++jf)
            #pragma unroll
            for (int r = 0; r < 4; ++r) {
                int j = j0w + jf * 16 + gr * 4 + r;
                float s = accs[uf][jf][r] * 0.125f;
                s = (j <= su[uf]) ? s : -1e30f;
                accs[uf][jf][r] = s;
                mm = fmaxf(mm, s);
            }
        mm = fmaxf(mm, __shfl_xor(mm, 16));
        mm = fmaxf(mm, __shfl_xor(mm, 32));
        float ll = 0.f;
        #pragma unroll
        for (int jf = 0; jf < 4; ++jf)
            #pragma unroll
            for (int r = 0; r < 4; ++r) {
                float e = __expf(accs[uf][jf][r] - mm);
                accs[uf][jf][r] = e;
                ll += e;
            }
        ll += __shfl_xor(ll, 16);
        ll += __shfl_xor(ll, 32);
        if (gr == 0) {
            int u = uf * 16 + l15;
            if (u < U_) {
                pm[((size_t)g * NCW_ + cw) * U_ + u] = mm;
                pl[((size_t)g * NCW_ + cw) * U_ + u] = ll;
            }
        }
    }

    // ---- pack P to bf16, per-wave LDS [u][j] ----
    short* pw = &pls[wid][0];
    #pragma unroll
    for (int uf = 0; uf < 3; ++uf)
        #pragma unroll
        for (int jf = 0; jf < 4; ++jf) {
            uint2 wv;
            wv.x = pack2(accs[uf][jf][0], accs[uf][jf][1]);
            wv.y = pack2(accs[uf][jf][2], accs[uf][jf][3]);
            *(uint2*)&pw[(uf * 16 + l15) * 72 + jf * 16 + gr * 4] = wv;
        }

    // ---- PV: O^T[d][u] = V^T @ P^T ----
    bf16x8 va[4][2], pb[3][2];
    #pragma unroll
    for (int df = 0; df < 4; ++df)
        #pragma unroll
        for (int ks = 0; ks < 2; ++ks)
            va[df][ks] = *(const bf16x8*)(vt + ((size_t)g * HD_ + df * 16 + l15) * T_ + j0w + ks * 32 + gr * 8);
    #pragma unroll
    for (int uf = 0; uf < 3; ++uf)
        #pragma unroll
        for (int ks = 0; ks < 2; ++ks)
            pb[uf][ks] = *(bf16x8*)&pw[(uf * 16 + l15) * 72 + ks * 32 + gr * 8];

    f32x4 acco[4][3];
    #pragma unroll
    for (int df = 0; df < 4; ++df)
        #pragma unroll
        for (int uf = 0; uf < 3; ++uf)
            acco[df][uf] = (f32x4){0.f, 0.f, 0.f, 0.f};
    #pragma unroll
    for (int df = 0; df < 4; ++df)
        #pragma unroll
        for (int uf = 0; uf < 3; ++uf) {
            acco[df][uf] = __builtin_amdgcn_mfma_f32_16x16x32_bf16(va[df][0], pb[uf][0], acco[df][uf], 0, 0, 0);
            acco[df][uf] = __builtin_amdgcn_mfma_f32_16x16x32_bf16(va[df][1], pb[uf][1], acco[df][uf], 0, 0, 0);
        }

    #pragma unroll
    for (int df = 0; df < 4; ++df)
        #pragma unroll
        for (int uf = 0; uf < 3; ++uf) {
            int u = uf * 16 + l15;
            if (u < U_) {
                float4 o;
                o.x = acco[df][uf][0]; o.y = acco[df][uf][1];
                o.z = acco[df][uf][2]; o.w = acco[df][uf][3];
                *(float4*)(po + (((size_t)g * NCW_ + cw) * U_ + u) * HD_ + df * 16 + gr * 4) = o;
            }
        }
}

// ---------------------------------------------------------------------------
// Combine: grid (g, u-quad). Dependency-free two-pass merge.
// ---------------------------------------------------------------------------
__global__ __launch_bounds__(256) void attn_combine(
    const float* __restrict__ pm, const float* __restrict__ pl,
    const float* __restrict__ po, float* __restrict__ selo)
{
    const int g = blockIdx.x;
    const int u = blockIdx.y * 4 + (threadIdx.x >> 6);
    const int d = threadIdx.x & 63;
    if (u >= U_) return;

    const float* pmg = pm + (size_t)g * NCW_ * U_ + u;
    const float* plg = pl + (size_t)g * NCW_ * U_ + u;

    float mc[NCW_];
    #pragma unroll
    for (int c = 0; c < NCW_; ++c) mc[c] = pmg[(size_t)c * U_];
    float m = -3e38f;
    #pragma unroll
    for (int c = 0; c < NCW_; ++c) m = fmaxf(m, mc[c]);

    float w[NCW_];
    #pragma unroll
    for (int c = 0; c < NCW_; ++c) w[c] = __expf(mc[c] - m);

    float l = 0.f;
    #pragma unroll
    for (int c = 0; c < NCW_; ++c) l += plg[(size_t)c * U_] * w[c];

    float o = 0.f;
    #pragma unroll
    for (int c = 0; c < NCW_; ++c)
        o += po[(((size_t)g * NCW_ + c) * U_ + u) * HD_ + d] * w[c];

    selo[((size_t)g * U_ + u) * HD_ + d] = o / l;
}

// ---------------------------------------------------------------------------
__global__ __launch_bounds__(256) void fill_kernel(
    const float* __restrict__ bo, float* __restrict__ out)
{
    const size_t i = (size_t)blockIdx.x * 256 + threadIdx.x;   // float4 index
    float4 bv = *(const float4*)(bo + ((i & 255) << 2));
    *(float4*)(out + i * 4) = bv;
}

__global__ __launch_bounds__(256) void oproj_kernel(
    const float* __restrict__ selo, const int* __restrict__ idxb,
    const float* __restrict__ Wo, float* __restrict__ out)
{
    __shared__ float sel[64];
    const int blk = blockIdx.x;
    const int h = (blk / U_) % H_;
    const int b = blk / (U_ * H_);
    const int t = idxb[blk];
    const int tid = threadIdx.x;
    if (tid < 64) sel[tid] = selo[(size_t)blk * HD_ + tid];
    __syncthreads();
    float* orow = out + ((size_t)b * T_ + t) * D_;
    #pragma unroll
    for (int rep = 0; rep < 4; ++rep) {
        int n = tid + rep * 256;
        float c = 0.f;
        #pragma unroll 8
        for (int dd = 0; dd < 64; ++dd)
            c += sel[dd] * Wo[(size_t)(h * HD_ + dd) * D_ + n];
        atomicAdd(orow + n, c);
    }
}

// ---------------------------------------------------------------------------
extern "C" void kernel_launch(void* const* d_in, const int* in_sizes, int n_in,
                              void* d_out, int out_size, void* d_ws, size_t ws_size,
                              hipStream_t stream)
{
    const float* x  = (const float*)d_in[0];
    const float* Wq = (const float*)d_in[1];
    const float* bq = (const float*)d_in[2];
    const float* Wk = (const float*)d_in[3];
    const float* bk = (const float*)d_in[4];
    const float* Wv = (const float*)d_in[5];
    const float* bv = (const float*)d_in[6];
    const float* Wo = (const float*)d_in[7];
    const float* bo = (const float*)d_in[8];
    float* out = (float*)d_out;

    char* ws = (char*)d_ws;
    short* xh    = (short*)(ws);                        // 16,777,216
    short* xl    = (short*)(ws + 16777216);             // 16,777,216  end 33,554,432
    short* wq2   = (short*)(ws + 33554432);             //  4,194,304  end 37,748,736  [wh;wl]
    short* wkvt  = (short*)(ws + 37748736);             //  4,194,304  end 41,943,040
    short* kb    = (short*)(ws + 41943040);             // 16,777,216  end 58,720,256
    short* vt    = (short*)(ws + 58720256);             // 16,777,216  end 75,497,472
    float* qnorm = (float*)(ws + 75497472);             //    524,288  end 76,021,760
    int*   idxb  = (int*)  (ws + 76021760);             //     16,384  end 76,038,144
    float* selo  = (float*)(ws + 76038144);             //    622,592  end 76,660,736
    short* qbuf  = (short*)(ws + 76660736);             // 16,777,216  end 93,437,952
    // partials overlay xh/xl (dead after the GEMMs):
    float* po    = (float*)(ws);                        // 19,922,944
    float* pm    = (float*)(ws + 19922944);             //    311,296
    float* pl    = (float*)(ws + 20234240);             //    311,296

    convx_kernel<<<M_ * D_ / 1024, 256, 0, stream>>>(x, xh, xl);
    convw_kernel<<<dim3(32, 32, 3), 256, 0, stream>>>(Wq, Wk, Wv, wq2, wkvt);
    gemm_fused<<<1536, 256, 0, stream>>>(xh, xl, wq2, wkvt, bq, bk, bv,
                                         qnorm, qbuf, kb, vt);
    topk_kernel<<<B_ * H_, 64, 0, stream>>>(qnorm, idxb);
    attn_part<<<64 * 8, 256, 0, stream>>>(qbuf, kb, vt, idxb, pm, pl, po);
    attn_combine<<<dim3(B_ * H_, (U_ + 3) / 4), 256, 0, stream>>>(pm, pl, po, selo);
    fill_kernel<<<(M_ * D_ / 4) / 256, 256, 0, stream>>>(bo, out);
    oproj_kernel<<<B_ * H_ * U_, 256, 0, stream>>>(selo, idxb, Wo, out);
}